// Round 9
// baseline (390.143 us; speedup 1.0000x reference)
//
#include <hip/hip_runtime.h>
#include <hip/hip_bf16.h>

// ---------------- constants ----------------
#define B_SZ   4
#define SEQ    2048
#define DM     1024
#define DIN    2048
#define DST    64
#define NH     32
#define HD     64
#define DPROJ  4256   // source W_in width
#define NPROJ  4224   // z + xBC = 33*128 (dt cols excluded from GEMM1)
#define MROWS  (B_SZ*SEQ)  // 8192
#define QC     64     // scan chunk length
#define NC     (SEQ/QC)   // 32 chunks

// Tiled operand layout for MFMA GEMMs ("fragment order"):
//   each (16-row, 32-col) tile = 512 contiguous bf16, lane-linear for both
//   global_load_lds staging and ds_read_b128 fragment reads.

typedef __attribute__((ext_vector_type(8))) __bf16 bf16x8;
typedef __attribute__((ext_vector_type(4))) __bf16 bf16x4;
typedef __attribute__((ext_vector_type(4))) float  floatx4;

// XOR-swizzled index into a 64x64 bf16 LDS tile (8-elem granules rotated by row&7)
__device__ __forceinline__ int swz(int row, int col) {
    return row * 64 + ((((col >> 3) ^ (row & 7)) << 3) | (col & 7));
}
__device__ __forceinline__ float bfbits2f(unsigned short u) {
    return __uint_as_float(((unsigned int)u) << 16);
}
__device__ __forceinline__ float silu_f(float v) { return v / (1.f + __expf(-v)); }

// ---------------- merged: 2 tiled weight transposes + x->tiled bf16 + dt proj -------
// grid: [0,1056) W_in^T (33x32) | [1056,1568) W_out^T*norm_w (8x64) | [1568,2080) cvt_dt
__global__ __launch_bounds__(256) void prep_cvt_kernel(const float* __restrict__ x,
                                                       const float* __restrict__ W_in,
                                                       const float* __restrict__ W_out,
                                                       const float* __restrict__ norm_w,
                                                       __bf16* __restrict__ xbf,
                                                       __bf16* __restrict__ WinT,
                                                       __bf16* __restrict__ WoutT,
                                                       float* __restrict__ dtraw) {
    __shared__ float smem[16 * 132 + 4096];   // covers tile[32][129] or xs+dtw
    const int bid = blockIdx.x, tid = threadIdx.x;
    if (bid < 1568) {
        // ---- tiled transpose (+ optional norm_w row scale) ----
        float (*tile)[129] = (float (*)[129])smem;
        const float* src; __bf16* dst; const float* scal; int Ksrc, Csrc, mb, kb;
        if (bid < 1056) {
            mb = bid >> 5; kb = bid & 31;
            src = W_in; dst = WinT; scal = nullptr; Ksrc = DM; Csrc = DPROJ;
        } else {
            int t = bid - 1056; mb = t >> 6; kb = t & 63;
            src = W_out; dst = WoutT; scal = norm_w; Ksrc = DIN; Csrc = DM;
        }
        const int K32 = Ksrc >> 5;
        #pragma unroll
        for (int i = 0; i < 4; i++) {
            int idx = tid + 256 * i;                 // 1024 float4 = 32 rows x 128 cols
            int kl = idx >> 5, c4 = idx & 31;
            int n = mb * 128 + c4 * 4;
            float4 v = make_float4(0.f, 0.f, 0.f, 0.f);
            if (n < Csrc) v = *(const float4*)(src + (size_t)(kb * 32 + kl) * Csrc + n);
            if (scal) { float s = scal[kb * 32 + kl]; v.x *= s; v.y *= s; v.z *= s; v.w *= s; }
            tile[kl][c4 * 4 + 0] = v.x; tile[kl][c4 * 4 + 1] = v.y;
            tile[kl][c4 * 4 + 2] = v.z; tile[kl][c4 * 4 + 3] = v.w;
        }
        __syncthreads();
        #pragma unroll
        for (int i = 0; i < 2; i++) {
            int c = tid + 256 * i;                   // 512 granules
            int sub = c >> 6, ln = c & 63, q = ln >> 4, lmn = ln & 15;
            bf16x8 o;
            #pragma unroll
            for (int e = 0; e < 8; e++) o[e] = (__bf16)tile[q * 8 + e][sub * 16 + lmn];
            *(bf16x8*)(dst + ((((size_t)(mb * 8 + sub)) * K32 + kb) << 9) + (ln << 3)) = o;
        }
        return;
    }
    // ---- fused x -> tiled bf16 + fp32 dt projection (one 16-row slab) ----
    float (*xs)[132] = (float (*)[132])smem;
    float* dtw = smem + 16 * 132;
    const int slabi = bid - 1568;
    const int r0 = slabi * 16;
    const int lm = tid & 15, pos = tid >> 4;              // granule writer mapping
    const int rr = tid >> 4, h2 = (tid & 15) * 2;         // dt accumulator mapping
    __bf16* slab = xbf + (size_t)slabi * (16 * DM);

    float a0 = 0.f, a1 = 0.f;
    for (int kc = 0; kc < 8; kc++) {
        #pragma unroll
        for (int i = 0; i < 2; i++) {
            int idx = tid + 256 * i;                       // 512 float4
            int row = idx >> 5, c4 = idx & 31;
            float4 v = ((const float4*)(x + (size_t)(r0 + row) * DM + kc * 128))[c4];
            xs[row][c4 * 4 + 0] = v.x; xs[row][c4 * 4 + 1] = v.y;
            xs[row][c4 * 4 + 2] = v.z; xs[row][c4 * 4 + 3] = v.w;
        }
        #pragma unroll
        for (int i = 0; i < 16; i++) {
            int idx = tid + 256 * i;                       // dtw[j][h] from W_in dt cols
            dtw[idx] = W_in[(size_t)(kc * 128 + (idx >> 5)) * DPROJ + NPROJ + (idx & 31)];
        }
        __syncthreads();
        {
            bf16x8 o;
            #pragma unroll
            for (int e = 0; e < 8; e++) o[e] = (__bf16)xs[lm][pos * 8 + e];
            int kb = kc * 4 + (pos >> 2), q = pos & 3;
            *(bf16x8*)(slab + (size_t)(kb * 64 + q * 16 + lm) * 8) = o;
        }
        for (int j = 0; j < 128; j++) {
            float xv = xs[rr][j];
            a0 = fmaf(xv, dtw[j * 32 + h2], a0);
            a1 = fmaf(xv, dtw[j * 32 + h2 + 1], a1);
        }
        __syncthreads();
    }
    dtraw[(size_t)(r0 + rr) * NH + h2]     = a0;
    dtraw[(size_t)(r0 + rr) * NH + h2 + 1] = a1;
}

// ---------------- GEMM body on TILED operands: C[M][N] = A * Bt^T --------------------
template<int STORE_BF16>
__device__ __forceinline__ void gemm_body(const __bf16* __restrict__ A,
                                          const __bf16* __restrict__ Bt,
                                          float* __restrict__ Cf,
                                          __bf16* __restrict__ Cb,
                                          const float* __restrict__ rowscale,
                                          int N, int K, int mb, int nb) {
    __shared__ __align__(16) __bf16 As[4096];
    __shared__ __align__(16) __bf16 Bs[4096];
    const int tid = threadIdx.x;
    const int wave = tid >> 6, lane = tid & 63;
    const int lm = lane & 15, lq = lane >> 4;
    const int K32 = K >> 5;

    floatx4 acc[4][4] = {};

    for (int kb = 0; kb < K32; kb++) {
        #pragma unroll
        for (int r = 0; r < 2; r++) {
            int c = tid + (r << 8);              // 512 chunks of 16 B, lane-contiguous
            int sub = c >> 6, ln = c & 63;
            __builtin_amdgcn_global_load_lds(
                reinterpret_cast<const unsigned int*>(
                    A + ((((size_t)(mb * 8 + sub)) * K32 + kb) << 9) + (ln << 3)),
                reinterpret_cast<unsigned int*>(As + (size_t)c * 8), 16, 0, 0);
            __builtin_amdgcn_global_load_lds(
                reinterpret_cast<const unsigned int*>(
                    Bt + ((((size_t)(nb * 8 + sub)) * K32 + kb) << 9) + (ln << 3)),
                reinterpret_cast<unsigned int*>(Bs + (size_t)c * 8), 16, 0, 0);
        }
        __syncthreads();
        bf16x8 af[4], bfr[4];
        #pragma unroll
        for (int i = 0; i < 4; i++)
            af[i] = *(const bf16x8*)(As + ((((wave & 1) << 2) + i) << 9) + (lane << 3));
        #pragma unroll
        for (int i = 0; i < 4; i++)
            bfr[i] = *(const bf16x8*)(Bs + ((((wave >> 1) << 2) + i) << 9) + (lane << 3));
        #pragma unroll
        for (int mi = 0; mi < 4; mi++)
            #pragma unroll
            for (int ni = 0; ni < 4; ni++)
                acc[mi][ni] = __builtin_amdgcn_mfma_f32_16x16x32_bf16(af[mi], bfr[ni], acc[mi][ni], 0, 0, 0);
        __syncthreads();
    }

    const int wm = (wave & 1) << 6, wn = (wave >> 1) << 6;
    #pragma unroll
    for (int mi = 0; mi < 4; mi++) {
        #pragma unroll
        for (int r = 0; r < 4; r++) {
            int row = mb * 128 + wm + mi * 16 + lq * 4 + r;
            float s = 1.f;
            if (rowscale) s = rsqrtf(rowscale[row] * (1.f / (float)DIN) + 1e-5f);
            #pragma unroll
            for (int ni = 0; ni < 4; ni++) {
                int col = nb * 128 + wn + ni * 16 + lm;
                if (col < N) {
                    if (STORE_BF16) Cb[(size_t)row * N + col] = (__bf16)acc[mi][ni][r];
                    else            Cf[(size_t)row * N + col] = acc[mi][ni][r] * s;
                }
            }
        }
    }
}

// ---------------- GEMM1 (+ dt_prep + rowsum zeroing appended to the grid) ------------
// grid: [0,2112) gemm 64x33 | [2112,2240) dt_prep (b*NH+h) | [2240,2248) zero rowsum
__global__ __launch_bounds__(256) void gemm1_kernel(const __bf16* __restrict__ A,
                                                    const __bf16* __restrict__ Bt,
                                                    __bf16* __restrict__ Cb,
                                                    const float* __restrict__ dtraw,
                                                    const float* __restrict__ dt_bias,
                                                    const float* __restrict__ A_log,
                                                    float* __restrict__ dtv,
                                                    float* __restrict__ cum,
                                                    float* __restrict__ rowsum) {
    const int bid = blockIdx.x, tid = threadIdx.x;
    if (bid < 2112) {
        gemm_body<1>(A, Bt, nullptr, Cb, nullptr, NPROJ, DM, bid & 63, bid >> 6);
    } else if (bid < 2240) {
        // ---- dt prep: softplus + per-chunk inclusive cumsum of dt*A ----
        const int blk = bid - 2112;    // b*NH + h
        const int b = blk >> 5, h = blk & 31;
        const int wave = tid >> 6, lane = tid & 63;
        float Ah = -__expf(A_log[h]);
        float dtb = dt_bias[h];
        for (int c = wave; c < NC; c += 4) {
            int t = c * QC + lane;
            float u = dtraw[((size_t)b * SEQ + t) * NH + h] + dtb;
            float d = fmaxf(u, 0.f) + log1pf(__expf(-fabsf(u)));  // softplus, fp32
            float s = d * Ah;
            #pragma unroll
            for (int o = 1; o < 64; o <<= 1) {
                float v = __shfl_up(s, o);
                if (lane >= o) s += v;
            }
            size_t idx = (size_t)blk * SEQ + t;
            dtv[idx] = d;
            cum[idx] = s;
        }
    } else {
        float4 z = make_float4(0.f, 0.f, 0.f, 0.f);
        *(float4*)(rowsum + (size_t)(bid - 2240) * 1024 + tid * 4) = z;
    }
}

__global__ __launch_bounds__(256) void gemm2_kernel(const __bf16* __restrict__ A,
                                                    const __bf16* __restrict__ Bt,
                                                    float* __restrict__ Cf,
                                                    const float* __restrict__ rowscale) {
    gemm_body<0>(A, Bt, Cf, nullptr, rowscale, DM, DIN, blockIdx.x, blockIdx.y);
}

// ---------------- chunk state (MFMA, conv fused): S^T[p][n] = sum_s x~[s][p]*w_s*B~[s][n]
// x~, B~ = silu(conv(zx)) computed on the fly.  block = (b,c,head-quad); wave = one head.
__global__ __launch_bounds__(256) void chunk_state_kernel(const __bf16* __restrict__ zx,
                                                          const float* __restrict__ cw,
                                                          const float* __restrict__ cb,
                                                          const float* __restrict__ dtv,
                                                          const float* __restrict__ cum,
                                                          __bf16* __restrict__ Sbuf) {
    const int blk = blockIdx.x;            // ((b*NC)+c)*8 + hq
    const int hq = blk & 7;
    const int bc = blk >> 3;
    const int c = bc & (NC - 1), b = bc >> 5;
    const int tid = threadIdx.x;
    const int wave = tid >> 6, lane = tid & 63;
    const int lm = lane & 15, q = lane >> 4;
    const int h = hq * 4 + wave;

    __shared__ __align__(16) __bf16 sBt[4096];      // B^T [n][s], swizzled
    __shared__ __align__(16) __bf16 sXw[4][4096];   // (w*x)^T [p][s], swizzled

    const __bf16* zb = zx + (size_t)b * SEQ * NPROJ;
    // ---- stage B^T with fused conv: thread = (row-group rg of 8, col-pair cs) ----
    {
        const int rg = tid >> 5, cs = tid & 31;
        const int n0 = 2 * cs;
        float4 wA = *(const float4*)(cw + (size_t)(2048 + n0) * 4);
        float  bA = cb[2048 + n0];
        float4 wB = *(const float4*)(cw + (size_t)(2048 + n0 + 1) * 4);
        float  bB = cb[2048 + n0 + 1];
        unsigned int rv[11];
        const int tbase = c * QC + rg * 8 - 3;
        #pragma unroll
        for (int i = 0; i < 11; i++) {
            int t = tbase + i;
            rv[i] = (t >= 0) ? *(const unsigned int*)(zb + (size_t)t * NPROJ + 4096 + n0) : 0u;
        }
        bf16x8 olo, ohi;
        #pragma unroll
        for (int sl = 0; sl < 8; sl++) {
            float xl[4], xh[4];
            #pragma unroll
            for (int k = 0; k < 4; k++) {
                unsigned int u = rv[sl + k];
                xl[k] = bfbits2f((unsigned short)(u & 0xffff));
                xh[k] = bfbits2f((unsigned short)(u >> 16));
            }
            olo[sl] = (__bf16)silu_f(bA + wA.x*xl[0] + wA.y*xl[1] + wA.z*xl[2] + wA.w*xl[3]);
            ohi[sl] = (__bf16)silu_f(bB + wB.x*xh[0] + wB.y*xh[1] + wB.z*xh[2] + wB.w*xh[3]);
        }
        *(bf16x8*)&sBt[swz(n0,     rg * 8)] = olo;
        *(bf16x8*)&sBt[swz(n0 + 1, rg * 8)] = ohi;
    }
    // ---- stage (w*x~)^T per wave with fused conv: lane = (col-group cg, row-group rg)
    const float* cump = cum + (size_t)(b * NH + h) * SEQ + (size_t)c * QC;
    const float* dtp  = dtv + (size_t)(b * NH + h) * SEQ + (size_t)c * QC;
    {
        const int cg = lane >> 3, rg = lane & 7;
        const int jx = h * 64 + cg * 8;            // conv index; zx col = 2048 + jx
        float w4[8][4], bs[8];
        #pragma unroll
        for (int e = 0; e < 8; e++) {
            float4 w = *(const float4*)(cw + (size_t)(jx + e) * 4);
            w4[e][0] = w.x; w4[e][1] = w.y; w4[e][2] = w.z; w4[e][3] = w.w;
            bs[e] = cb[jx + e];
        }
        float rf[11][8];
        const int tbase = c * QC + rg * 8 - 3;
        #pragma unroll
        for (int i = 0; i < 11; i++) {
            int t = tbase + i;
            if (t >= 0) {
                bf16x8 v = *(const bf16x8*)(zb + (size_t)t * NPROJ + 2048 + jx);
                #pragma unroll
                for (int e = 0; e < 8; e++) rf[i][e] = (float)v[e];
            } else {
                #pragma unroll
                for (int e = 0; e < 8; e++) rf[i][e] = 0.f;
            }
        }
        float clast = cump[63];
        float wdt[8];
        #pragma unroll
        for (int sl = 0; sl < 8; sl++) {
            int s = rg * 8 + sl;
            wdt[sl] = dtp[s] * __expf(clast - cump[s]);
        }
        #pragma unroll
        for (int e = 0; e < 8; e++) {
            bf16x8 o;
            #pragma unroll
            for (int sl = 0; sl < 8; sl++) {
                float v = bs[e] + w4[e][0]*rf[sl][e] + w4[e][1]*rf[sl+1][e]
                                + w4[e][2]*rf[sl+2][e] + w4[e][3]*rf[sl+3][e];
                o[sl] = (__bf16)(silu_f(v) * wdt[sl]);
            }
            *(bf16x8*)&sXw[wave][swz(cg * 8 + e, rg * 8)] = o;
        }
    }
    __syncthreads();

    floatx4 acc[4][4] = {};
    #pragma unroll
    for (int kb = 0; kb < 2; kb++) {
        bf16x8 aX[4], bB[4];
        #pragma unroll
        for (int pi = 0; pi < 4; pi++)
            aX[pi] = *(const bf16x8*)(&sXw[wave][swz(pi * 16 + lm, kb * 32 + q * 8)]);
        #pragma unroll
        for (int ni = 0; ni < 4; ni++)
            bB[ni] = *(const bf16x8*)(&sBt[swz(ni * 16 + lm, kb * 32 + q * 8)]);
        #pragma unroll
        for (int pi = 0; pi < 4; pi++)
            #pragma unroll
            for (int ni = 0; ni < 4; ni++)
                acc[pi][ni] = __builtin_amdgcn_mfma_f32_16x16x32_bf16(aX[pi], bB[ni], acc[pi][ni], 0, 0, 0);
    }
    __bf16* Sp = Sbuf + ((size_t)(b * NC + c) * NH + h) * (HD * DST);
    #pragma unroll
    for (int pi = 0; pi < 4; pi++)
        #pragma unroll
        for (int r = 0; r < 4; r++) {
            int p = pi * 16 + q * 4 + r;
            #pragma unroll
            for (int ni = 0; ni < 4; ni++)
                Sp[p * 64 + ni * 16 + lm] = (__bf16)acc[pi][ni][r];
        }
}

// ---------------- pass 2: inter-chunk state recurrence (in place, 512 blocks) -------
__global__ __launch_bounds__(256) void state_scan_kernel(__bf16* __restrict__ Sbuf,
                                                         const float* __restrict__ cum) {
    int blk = blockIdx.x >> 2;     // b*NH + h
    int part = blockIdx.x & 3;
    int b = blk >> 5, h = blk & 31;
    int off = part * 1024 + threadIdx.x * 4;
    float run[4];
    #pragma unroll
    for (int n = 0; n < 4; n++) run[n] = 0.f;
    for (int c = 0; c < NC; c++) {
        __bf16* Sp = Sbuf + ((size_t)(b * NC + c) * NH + h) * (HD * DST) + off;
        bf16x4 sv = *(const bf16x4*)Sp;
        float tmp[4];
        #pragma unroll
        for (int n = 0; n < 4; n++) tmp[n] = (float)sv[n];
        bf16x4 ov;
        #pragma unroll
        for (int n = 0; n < 4; n++) ov[n] = (__bf16)run[n];
        *(bf16x4*)Sp = ov;                                  // slot c <- state before chunk c
        float P = __expf(cum[(size_t)blk * SEQ + c * QC + QC - 1]);
        #pragma unroll
        for (int n = 0; n < 4; n++) run[n] = fmaf(run[n], P, tmp[n]);
    }
}

// ---------------- chunk output (MFMA, conv fused) + silu(z) gate + rowsum -----------
// Y = exp(cum_t)*C~@S_prev + (M o C~@B~^T + D*I)@X~ ; g = Y*silu(z) -> tiled yf
__global__ __launch_bounds__(128) void chunk_out_kernel(const __bf16* __restrict__ zx,
                                                        const float* __restrict__ cw,
                                                        const float* __restrict__ cb,
                                                        const float* __restrict__ dtv,
                                                        const float* __restrict__ cum,
                                                        const __bf16* __restrict__ Sbuf,
                                                        const float* __restrict__ Dv,
                                                        float* __restrict__ rowsum,
                                                        __bf16* __restrict__ y) {
    const int blk = blockIdx.x;           // ((b*NC)+c)*16 + hp
    const int hp = blk & 15;
    const int bc = blk >> 4;
    const int c = bc & (NC - 1), b = bc >> 5;
    const int tid = threadIdx.x;
    const int wave = tid >> 6, lane = tid & 63;
    const int lm = lane & 15, q = lane >> 4;
    const int h = hp * 2 + wave;

    __shared__ __align__(16) __bf16 smem[16384];     // 32 KB
    __bf16* sB  = smem;                              // B~ [s][n] swizzled (shared)
    __bf16* sC  = smem + 4096;                       // C~ [t][n] swizzled (shared)
    __bf16* sXt = smem + 8192 + (wave << 12);        // x~^T [p][s] swizzled (per wave)
    __bf16* sP  = smem + (wave << 12);               // P aliases sB (w0) / sC (w1)

    const __bf16* zb = zx + (size_t)b * SEQ * NPROJ;
    const size_t rowbase = (size_t)b * SEQ + (size_t)c * QC;
    // ---- stage B~ (wave 0) / C~ (wave 1) with fused conv: lane = (cg, rg) ----
    {
        const int cg = lane >> 3, rg = lane & 7;
        const int jx = 2048 + wave * 64 + cg * 8;    // conv index (B: 2048.., C: 2112..)
        __bf16* sDst = wave ? sC : sB;
        float w4[8][4], bs[8];
        #pragma unroll
        for (int e = 0; e < 8; e++) {
            float4 w = *(const float4*)(cw + (size_t)(jx + e) * 4);
            w4[e][0] = w.x; w4[e][1] = w.y; w4[e][2] = w.z; w4[e][3] = w.w;
            bs[e] = cb[jx + e];
        }
        float rf[11][8];
        const int tbase = c * QC + rg * 8 - 3;
        #pragma unroll
        for (int i = 0; i < 11; i++) {
            int t = tbase + i;
            if (t >= 0) {
                bf16x8 v = *(const bf16x8*)(zb + (size_t)t * NPROJ + 2048 + jx);
                #pragma unroll
                for (int e = 0; e < 8; e++) rf[i][e] = (float)v[e];
            } else {
                #pragma unroll
                for (int e = 0; e < 8; e++) rf[i][e] = 0.f;
            }
        }
        #pragma unroll
        for (int sl = 0; sl < 8; sl++) {
            bf16x8 o;
            #pragma unroll
            for (int e = 0; e < 8; e++) {
                float v = bs[e] + w4[e][0]*rf[sl][e] + w4[e][1]*rf[sl+1][e]
                                + w4[e][2]*rf[sl+2][e] + w4[e][3]*rf[sl+3][e];
                o[e] = (__bf16)silu_f(v);
            }
            *(bf16x8*)&sDst[swz(rg * 8 + sl, cg * 8)] = o;
        }
    }
    // ---- stage x~^T per wave with fused conv (transposed [p][s]) ----
    {
        const int cg = lane >> 3, rg = lane & 7;
        const int jx = h * 64 + cg * 8;              // conv index; zx col = 2048 + jx
        float w4[8][4], bs[8];
        #pragma unroll
        for (int e = 0; e < 8; e++) {
            float4 w = *(const float4*)(cw + (size_t)(jx + e) * 4);
            w4[e][0] = w.x; w4[e][1] = w.y; w4[e][2] = w.z; w4[e][3] = w.w;
            bs[e] = cb[jx + e];
        }
        float rf[11][8];
        const int tbase = c * QC + rg * 8 - 3;
        #pragma unroll
        for (int i = 0; i < 11; i++) {
            int t = tbase + i;
            if (t >= 0) {
                bf16x8 v = *(const bf16x8*)(zb + (size_t)t * NPROJ + 2048 + jx);
                #pragma unroll
                for (int e = 0; e < 8; e++) rf[i][e] = (float)v[e];
            } else {
                #pragma unroll
                for (int e = 0; e < 8; e++) rf[i][e] = 0.f;
            }
        }
        #pragma unroll
        for (int e = 0; e < 8; e++) {
            bf16x8 o;
            #pragma unroll
            for (int sl = 0; sl < 8; sl++) {
                float v = bs[e] + w4[e][0]*rf[sl][e] + w4[e][1]*rf[sl+1][e]
                                + w4[e][2]*rf[sl+2][e] + w4[e][3]*rf[sl+3][e];
                o[sl] = (__bf16)silu_f(v);
            }
            *(bf16x8*)&sXt[swz(cg * 8 + e, rg * 8)] = o;
        }
    }
    __syncthreads();

    const float* cump = cum + (size_t)(b * NH + h) * SEQ + (size_t)c * QC;
    const float* dtp  = dtv + (size_t)(b * NH + h) * SEQ + (size_t)c * QC;
    float cumv = cump[lane], dtvv = dtp[lane];
    float ct[4][4];
    #pragma unroll
    for (int ti = 0; ti < 4; ti++)
        #pragma unroll
        for (int r = 0; r < 4; r++)
            ct[ti][r] = __shfl(cumv, ti * 16 + q * 4 + r);
    float cums_l[4], dtv_l[4];
    #pragma unroll
    for (int si = 0; si < 4; si++) {
        cums_l[si] = __shfl(cumv, si * 16 + lm);
        dtv_l[si]  = __shfl(dtvv, si * 16 + lm);
    }

    bf16x8 afC[4][2];
    #pragma unroll
    for (int ti = 0; ti < 4; ti++)
        #pragma unroll
        for (int kb = 0; kb < 2; kb++)
            afC[ti][kb] = *(const bf16x8*)(&sC[swz(ti * 16 + lm, kb * 32 + q * 8)]);

    // G = C~ @ B~^T (triangular tiles si<=ti)
    floatx4 accG[4][4] = {};
    #pragma unroll
    for (int kb = 0; kb < 2; kb++) {
        bf16x8 bfB[4];
        #pragma unroll
        for (int si = 0; si < 4; si++)
            bfB[si] = *(const bf16x8*)(&sB[swz(si * 16 + lm, kb * 32 + q * 8)]);
        #pragma unroll
        for (int ti = 0; ti < 4; ti++)
            #pragma unroll
            for (int si = 0; si < 4; si++)
                if (si <= ti)
                    accG[ti][si] = __builtin_amdgcn_mfma_f32_16x16x32_bf16(afC[ti][kb], bfB[si], accG[ti][si], 0, 0, 0);
    }
    __syncthreads();   // all waves done reading sB/sC -> safe to overwrite with P

    // mask + decay -> P (bf16, swizzled [t][s]); D folded onto the diagonal
    float Dh = Dv[h];
    #pragma unroll
    for (int ti = 0; ti < 4; ti++)
        #pragma unroll
        for (int si = 0; si < 4; si++) {
            if (si > ti) continue;
            #pragma unroll
            for (int r = 0; r < 4; r++) {
                int t = ti * 16 + q * 4 + r;
                float arg = fminf(ct[ti][r] - cums_l[si], 0.f);
                float val = dtv_l[si] * __expf(arg) * accG[ti][si][r];
                if (ti == si) {
                    if (lm > q * 4 + r) val = 0.f;
                    else if (lm == q * 4 + r) val += Dh;
                }
                sP[swz(t, si * 16 + lm)] = (__bf16)val;
            }
        }
    #pragma unroll
    for (int r = 0; r < 4; r++) {   // zero tiles (0,1) and (2,3)
        sP[swz(q * 4 + r, 16 + lm)] = (__bf16)0.f;
        sP[swz(32 + q * 4 + r, 48 + lm)] = (__bf16)0.f;
    }
    __syncthreads();

    // inter-chunk: Y = C~ @ S_prev, then row-scale by exp(cum_t)
    floatx4 accY[4][4] = {};
    const __bf16* Sp = Sbuf + ((size_t)(b * NC + c) * NH + h) * (HD * DST);
    #pragma unroll
    for (int kb = 0; kb < 2; kb++) {
        bf16x8 bS[4];
        #pragma unroll
        for (int pi = 0; pi < 4; pi++)
            bS[pi] = *(const bf16x8*)(Sp + (pi * 16 + lm) * 64 + kb * 32 + q * 8);
        #pragma unroll
        for (int ti = 0; ti < 4; ti++)
            #pragma unroll
            for (int pi = 0; pi < 4; pi++)
                accY[ti][pi] = __builtin_amdgcn_mfma_f32_16x16x32_bf16(afC[ti][kb], bS[pi], accY[ti][pi], 0, 0, 0);
    }
    #pragma unroll
    for (int ti = 0; ti < 4; ti++)
        #pragma unroll
        for (int r = 0; r < 4; r++) {
            float e = __expf(ct[ti][r]);
            #pragma unroll
            for (int pi = 0; pi < 4; pi++)
                accY[ti][pi][r] *= e;
        }

    // intra: Y += P @ X~ (skip fully-masked k-blocks)
    #pragma unroll
    for (int kb = 0; kb < 2; kb++) {
        bf16x8 bX[4];
        #pragma unroll
        for (int pi = 0; pi < 4; pi++)
            bX[pi] = *(const bf16x8*)(&sXt[swz(pi * 16 + lm, kb * 32 + q * 8)]);
        #pragma unroll
        for (int ti = 0; ti < 4; ti++) {
            if (ti < 2 * kb) continue;
            bf16x8 aP = *(const bf16x8*)(&sP[swz(ti * 16 + lm, kb * 32 + q * 8)]);
            #pragma unroll
            for (int pi = 0; pi < 4; pi++)
                accY[ti][pi] = __builtin_amdgcn_mfma_f32_16x16x32_bf16(aP, bX[pi], accY[ti][pi], 0, 0, 0);
        }
    }

    // gate with silu(z), store into TILED yf, accumulate rowsum
    const int R4v = (int)(rowbase >> 4);
    #pragma unroll
    for (int ti = 0; ti < 4; ti++) {
        __bf16* slab = y + (size_t)(R4v + ti) * 32768;
        #pragma unroll
        for (int r = 0; r < 4; r++) {
            int t = ti * 16 + q * 4 + r;
            const __bf16* zrow = zx + (rowbase + t) * NPROJ + h * 64;
            float rs = 0.f;
            #pragma unroll
            for (int pi = 0; pi < 4; pi++) {
                float zv = (float)zrow[pi * 16 + lm];
                float g = accY[ti][pi][r] * silu_f(zv);
                rs += g * g;
                int kbC = h * 2 + (pi >> 1);
                int qC  = ((pi & 1) << 1) + (lm >> 3);
                slab[kbC * 512 + qC * 128 + (lm & 7) + (q * 4 + r) * 8] = (__bf16)g;
            }
            rs += __shfl_xor(rs, 1);
            rs += __shfl_xor(rs, 2);
            rs += __shfl_xor(rs, 4);
            rs += __shfl_xor(rs, 8);
            if (lm == 0) atomicAdd(&rowsum[rowbase + t], rs);
        }
    }
}

// ---------------- launch ----------------
extern "C" void kernel_launch(void* const* d_in, const int* in_sizes, int n_in,
                              void* d_out, int out_size, void* d_ws, size_t ws_size,
                              hipStream_t stream) {
    const float* x       = (const float*)d_in[0];
    const float* W_in    = (const float*)d_in[1];
    const float* conv_w  = (const float*)d_in[2];
    const float* conv_b  = (const float*)d_in[3];
    const float* dt_bias = (const float*)d_in[4];
    const float* A_log   = (const float*)d_in[5];
    const float* Dv      = (const float*)d_in[6];
    const float* norm_w  = (const float*)d_in[7];
    const float* W_out   = (const float*)d_in[8];
    float* out = (float*)d_out;

    char* ws = (char*)d_ws;
    size_t off = 0;
    auto take = [&](size_t bytes) { void* p = ws + off; off = (off + bytes + 255) & ~(size_t)255; return p; };
    __bf16* xbf    = (__bf16*)take((size_t)MROWS * DM * 2);          // 16.8 MB (tiled)
    __bf16* WinT   = (__bf16*)take((size_t)NPROJ * DM * 2);          //  8.7 MB (tiled)
    __bf16* WoutT  = (__bf16*)take((size_t)DM * DIN * 2);            //  4.2 MB (tiled, *norm_w)
    __bf16* zx     = (__bf16*)take((size_t)MROWS * NPROJ * 2);       // 69.2 MB (row-major)
    __bf16* yf     = (__bf16*)take((size_t)MROWS * DIN * 2);         // 33.6 MB (tiled, gated)
    float*  dtraw  = (float*) take((size_t)MROWS * NH * 4);          //  1.0 MB
    float*  dtv    = (float*) take((size_t)B_SZ * NH * SEQ * 4);     //  1.0 MB
    float*  cum    = (float*) take((size_t)B_SZ * NH * SEQ * 4);     //  1.0 MB
    __bf16* Sbuf   = (__bf16*)take((size_t)B_SZ * NC * NH * HD * DST * 2); // 33.6 MB
    float*  rowsum = (float*) take((size_t)MROWS * 4);               //  32 KB
    (void)ws_size;                                                    // total ~169 MB

    // 1. weight transposes + x->tiled bf16 + dt projection (merged)
    prep_cvt_kernel<<<dim3(2080), 256, 0, stream>>>(x, W_in, W_out, norm_w,
                                                    xbf, WinT, WoutT, dtraw);
    // 2. GEMM1 (zx = x @ W_in[:,:4224]) + dt softplus/cumsum + rowsum zeroing
    gemm1_kernel<<<dim3(2248), 256, 0, stream>>>(xbf, WinT, zx,
                                                 dtraw, dt_bias, A_log, dtv, cum, rowsum);
    // 3. chunk-local states via MFMA, conv fused (1024 blocks x 4 waves)
    chunk_state_kernel<<<dim3(B_SZ * NC * (NH / 4)), 256, 0, stream>>>(
        zx, conv_w, conv_b, dtv, cum, Sbuf);
    // 4. inter-chunk state recurrence (512 blocks)
    state_scan_kernel<<<dim3(B_SZ * NH * 4), 256, 0, stream>>>(Sbuf, cum);
    // 5. chunk outputs via MFMA, conv fused + gate + rowsum -> tiled yf
    chunk_out_kernel<<<dim3(B_SZ * NC * (NH / 2)), 128, 0, stream>>>(
        zx, conv_w, conv_b, dtv, cum, Sbuf, Dv, rowsum, yf);
    // 6. GEMM2: out = rmsnorm-scale(yf) @ (W_out*norm_w) (fp32 out)
    gemm2_kernel<<<dim3(MROWS / 128, DM / 128), 256, 0, stream>>>(yf, WoutT, out, rowsum);
}

// Round 10
// 351.649 us; speedup vs baseline: 1.1095x; 1.1095x over previous
//
#include <hip/hip_runtime.h>
#include <hip/hip_bf16.h>

// ---------------- constants ----------------
#define B_SZ   4
#define SEQ    2048
#define DM     1024
#define DIN    2048
#define DST    64
#define NH     32
#define HD     64
#define CONVD  2176
#define DPROJ  4256   // source W_in width
#define NPROJ  4224   // z + xBC = 33*128 (dt cols excluded from GEMM1)
#define MROWS  (B_SZ*SEQ)  // 8192
#define QC     64     // scan chunk length
#define NC     (SEQ/QC)   // 32 chunks

// Tiled operand layout for MFMA GEMMs ("fragment order"):
//   flat(r,k) = (((r>>4)*(K>>5) + (k>>5))*64 + ((k>>3)&3)*16 + (r&15))*8 + (k&7)
// => each (16-row, 32-col) tile = 512 contiguous bf16, lane-linear for both
//    global_load_lds staging and ds_read_b128 fragment reads.

typedef __attribute__((ext_vector_type(8))) __bf16 bf16x8;
typedef __attribute__((ext_vector_type(4))) __bf16 bf16x4;
typedef __attribute__((ext_vector_type(4))) float  floatx4;

// XOR-swizzled index into a 64x64 bf16 LDS tile (8-elem granules rotated by row&7)
__device__ __forceinline__ int swz(int row, int col) {
    return row * 64 + ((((col >> 3) ^ (row & 7)) << 3) | (col & 7));
}
__device__ __forceinline__ float bfbits2f(unsigned short u) {
    return __uint_as_float(((unsigned int)u) << 16);
}
__device__ __forceinline__ float silu_f(float v) { return v / (1.f + __expf(-v)); }

// ---------------- merged weight prep: dtWc compaction + 2 tiled transposes ----------
// grid: [0,128) dtw | [128,1184) W_in^T (33x32) | [1184,1696) W_out^T*norm_w (8x64)
__global__ __launch_bounds__(256) void prep_weights_kernel(const float* __restrict__ W_in,
                                                           const float* __restrict__ W_out,
                                                           const float* __restrict__ norm_w,
                                                           float* __restrict__ dtWc,
                                                           __bf16* __restrict__ WinT,
                                                           __bf16* __restrict__ WoutT) {
    __shared__ float tile[32][129];
    const int bid = blockIdx.x, tid = threadIdx.x;
    if (bid < 128) {
        int idx = bid * 256 + tid;
        int k = idx >> 5, h = idx & 31;
        dtWc[idx] = W_in[(size_t)k * DPROJ + NPROJ + h];
        return;
    }
    const float* src; __bf16* dst; const float* scal; int Ksrc, Csrc, mb, kb;
    if (bid < 128 + 1056) {
        int t = bid - 128; mb = t >> 5; kb = t & 31;
        src = W_in; dst = WinT; scal = nullptr; Ksrc = DM; Csrc = DPROJ;
    } else {
        int t = bid - 1184; mb = t >> 6; kb = t & 63;
        src = W_out; dst = WoutT; scal = norm_w; Ksrc = DIN; Csrc = DM;
    }
    const int K32 = Ksrc >> 5;
    #pragma unroll
    for (int i = 0; i < 4; i++) {
        int idx = tid + 256 * i;                 // 1024 float4 = 32 rows x 128 cols
        int kl = idx >> 5, c4 = idx & 31;
        int n = mb * 128 + c4 * 4;
        float4 v = make_float4(0.f, 0.f, 0.f, 0.f);
        if (n < Csrc) v = *(const float4*)(src + (size_t)(kb * 32 + kl) * Csrc + n);
        if (scal) { float s = scal[kb * 32 + kl]; v.x *= s; v.y *= s; v.z *= s; v.w *= s; }
        tile[kl][c4 * 4 + 0] = v.x; tile[kl][c4 * 4 + 1] = v.y;
        tile[kl][c4 * 4 + 2] = v.z; tile[kl][c4 * 4 + 3] = v.w;
    }
    __syncthreads();
    #pragma unroll
    for (int i = 0; i < 2; i++) {
        int c = tid + 256 * i;                   // 512 granules
        int sub = c >> 6, ln = c & 63, q = ln >> 4, lmn = ln & 15;
        bf16x8 o;
        #pragma unroll
        for (int e = 0; e < 8; e++) o[e] = (__bf16)tile[q * 8 + e][sub * 16 + lmn];
        *(bf16x8*)(dst + ((((size_t)(mb * 8 + sub)) * K32 + kb) << 9) + (ln << 3)) = o;
    }
}

// ---------------- fused: x -> TILED bf16 + fp32 dt projection (4 rows/block) --------
__global__ __launch_bounds__(256) void cvt_dt_kernel(const float* __restrict__ x,
                                                     const float* __restrict__ dtWc,
                                                     __bf16* __restrict__ xbf,
                                                     float* __restrict__ dtraw) {
    __shared__ float xs[4][DM];
    __shared__ float red[4][8][32];
    const int row0 = blockIdx.x * 4;
    const int tid = threadIdx.x;
    #pragma unroll
    for (int r = 0; r < 4; r++) {
        float4 v = ((const float4*)(x + (size_t)(row0 + r) * DM))[tid];
        xs[r][tid * 4 + 0] = v.x; xs[r][tid * 4 + 1] = v.y;
        xs[r][tid * 4 + 2] = v.z; xs[r][tid * 4 + 3] = v.w;
    }
    __syncthreads();
    // tiled granule writes (512 granules, 2/thread)
    __bf16* slab = xbf + (size_t)(row0 >> 4) * (16 * DM);
    const int lmb = row0 & 15;
    #pragma unroll
    for (int i = 0; i < 2; i++) {
        int g = tid + 256 * i;
        int r = g >> 7, pos = g & 127;
        int kb = pos >> 2, q = pos & 3;
        bf16x8 o;
        #pragma unroll
        for (int e = 0; e < 8; e++) o[e] = (__bf16)xs[r][pos * 8 + e];
        *(bf16x8*)(slab + (size_t)(kb * 64 + q * 16 + lmb + r) * 8) = o;
    }
    // dt projection: 32 heads x 8 partials
    const int part = tid >> 5, h = tid & 31;
    const float* wb = dtWc + part * 128 * 32 + h;
    const int kb0 = part * 128;
    float s0 = 0.f, s1 = 0.f, s2 = 0.f, s3 = 0.f;
    for (int j = 0; j < 128; j++) {
        float w = wb[j * 32];
        s0 = fmaf(xs[0][kb0 + j], w, s0);
        s1 = fmaf(xs[1][kb0 + j], w, s1);
        s2 = fmaf(xs[2][kb0 + j], w, s2);
        s3 = fmaf(xs[3][kb0 + j], w, s3);
    }
    red[0][part][h] = s0; red[1][part][h] = s1;
    red[2][part][h] = s2; red[3][part][h] = s3;
    __syncthreads();
    if (tid < 128) {
        int r = tid >> 5, hh = tid & 31;
        float s = 0.f;
        #pragma unroll
        for (int p = 0; p < 8; p++) s += red[r][p][hh];
        dtraw[(size_t)(row0 + r) * NH + hh] = s;
    }
}

// ---------------- GEMM body on TILED operands: C[M][N] = A * Bt^T --------------------
template<int STORE_BF16>
__device__ __forceinline__ void gemm_body(const __bf16* __restrict__ A,
                                          const __bf16* __restrict__ Bt,
                                          float* __restrict__ Cf,
                                          __bf16* __restrict__ Cb,
                                          const float* __restrict__ rowscale,
                                          int N, int K, int mb, int nb) {
    __shared__ __align__(16) __bf16 As[4096];
    __shared__ __align__(16) __bf16 Bs[4096];
    const int tid = threadIdx.x;
    const int wave = tid >> 6, lane = tid & 63;
    const int lm = lane & 15, lq = lane >> 4;
    const int K32 = K >> 5;

    floatx4 acc[4][4] = {};

    for (int kb = 0; kb < K32; kb++) {
        #pragma unroll
        for (int r = 0; r < 2; r++) {
            int c = tid + (r << 8);              // 512 chunks of 16 B, lane-contiguous
            int sub = c >> 6, ln = c & 63;
            __builtin_amdgcn_global_load_lds(
                reinterpret_cast<const unsigned int*>(
                    A + ((((size_t)(mb * 8 + sub)) * K32 + kb) << 9) + (ln << 3)),
                reinterpret_cast<unsigned int*>(As + (size_t)c * 8), 16, 0, 0);
            __builtin_amdgcn_global_load_lds(
                reinterpret_cast<const unsigned int*>(
                    Bt + ((((size_t)(nb * 8 + sub)) * K32 + kb) << 9) + (ln << 3)),
                reinterpret_cast<unsigned int*>(Bs + (size_t)c * 8), 16, 0, 0);
        }
        __syncthreads();
        bf16x8 af[4], bfr[4];
        #pragma unroll
        for (int i = 0; i < 4; i++)
            af[i] = *(const bf16x8*)(As + ((((wave & 1) << 2) + i) << 9) + (lane << 3));
        #pragma unroll
        for (int i = 0; i < 4; i++)
            bfr[i] = *(const bf16x8*)(Bs + ((((wave >> 1) << 2) + i) << 9) + (lane << 3));
        #pragma unroll
        for (int mi = 0; mi < 4; mi++)
            #pragma unroll
            for (int ni = 0; ni < 4; ni++)
                acc[mi][ni] = __builtin_amdgcn_mfma_f32_16x16x32_bf16(af[mi], bfr[ni], acc[mi][ni], 0, 0, 0);
        __syncthreads();
    }

    const int wm = (wave & 1) << 6, wn = (wave >> 1) << 6;
    #pragma unroll
    for (int mi = 0; mi < 4; mi++) {
        #pragma unroll
        for (int r = 0; r < 4; r++) {
            int row = mb * 128 + wm + mi * 16 + lq * 4 + r;
            float s = 1.f;
            if (rowscale) s = rsqrtf(rowscale[row] * (1.f / (float)DIN) + 1e-5f);
            #pragma unroll
            for (int ni = 0; ni < 4; ni++) {
                int col = nb * 128 + wn + ni * 16 + lm;
                if (col < N) {
                    if (STORE_BF16) Cb[(size_t)row * N + col] = (__bf16)acc[mi][ni][r];
                    else            Cf[(size_t)row * N + col] = acc[mi][ni][r] * s;
                }
            }
        }
    }
}

// ---------------- GEMM1 (+ dt_prep + rowsum zeroing appended to the grid) ------------
// grid: [0,2112) gemm 64x33 | [2112,2240) dt_prep (b*NH+h) | [2240,2248) zero rowsum
__global__ __launch_bounds__(256) void gemm1_kernel(const __bf16* __restrict__ A,
                                                    const __bf16* __restrict__ Bt,
                                                    __bf16* __restrict__ Cb,
                                                    const float* __restrict__ dtraw,
                                                    const float* __restrict__ dt_bias,
                                                    const float* __restrict__ A_log,
                                                    float* __restrict__ dtv,
                                                    float* __restrict__ cum,
                                                    float* __restrict__ rowsum) {
    const int bid = blockIdx.x, tid = threadIdx.x;
    if (bid < 2112) {
        gemm_body<1>(A, Bt, nullptr, Cb, nullptr, NPROJ, DM, bid & 63, bid >> 6);
    } else if (bid < 2240) {
        // ---- dt prep: softplus + per-chunk inclusive cumsum of dt*A ----
        const int blk = bid - 2112;    // b*NH + h
        const int b = blk >> 5, h = blk & 31;
        const int wave = tid >> 6, lane = tid & 63;
        float Ah = -__expf(A_log[h]);
        float dtb = dt_bias[h];
        for (int c = wave; c < NC; c += 4) {
            int t = c * QC + lane;
            float u = dtraw[((size_t)b * SEQ + t) * NH + h] + dtb;
            float d = fmaxf(u, 0.f) + log1pf(__expf(-fabsf(u)));  // softplus, fp32
            float s = d * Ah;
            #pragma unroll
            for (int o = 1; o < 64; o <<= 1) {
                float v = __shfl_up(s, o);
                if (lane >= o) s += v;
            }
            size_t idx = (size_t)blk * SEQ + t;
            dtv[idx] = d;
            cum[idx] = s;
        }
    } else {
        float4 z = make_float4(0.f, 0.f, 0.f, 0.f);
        *(float4*)(rowsum + (size_t)(bid - 2240) * 1024 + tid * 4) = z;
    }
}

__global__ __launch_bounds__(256) void gemm2_kernel(const __bf16* __restrict__ A,
                                                    const __bf16* __restrict__ Bt,
                                                    float* __restrict__ Cf,
                                                    const float* __restrict__ rowscale) {
    gemm_body<0>(A, Bt, Cf, nullptr, rowscale, DM, DIN, blockIdx.x, blockIdx.y);
}

// ---------------- depthwise causal conv (width 4) + silu, vectorized bf16x8 ----------
// thread = 8 channels x 8 timesteps.  grid (17, 64), block 256.
__global__ __launch_bounds__(256) void conv_silu_kernel(const __bf16* __restrict__ zx,
                                                        const float* __restrict__ cw,
                                                        const float* __restrict__ cb,
                                                        __bf16* __restrict__ out) {
    const int tid = threadIdx.x;
    const int tc = tid & 15, tt = tid >> 4;
    const int c0 = (blockIdx.x * 16 + tc) * 8;      // 0..2168
    const int tg = blockIdx.y * 16 + tt;            // 0..1023
    const int b = tg >> 8, t0 = (tg & 255) << 3;

    float xb[11][8];
    #pragma unroll
    for (int i = 0; i < 11; i++) {
        int t = t0 + i - 3;
        if (t >= 0) {
            bf16x8 v = *(const bf16x8*)(zx + ((size_t)(b * SEQ + t)) * NPROJ + DIN + c0);
            #pragma unroll
            for (int j = 0; j < 8; j++) xb[i][j] = (float)v[j];
        } else {
            #pragma unroll
            for (int j = 0; j < 8; j++) xb[i][j] = 0.f;
        }
    }
    float w0[8], w1[8], w2[8], w3[8], bias[8];
    #pragma unroll
    for (int j = 0; j < 8; j++) {
        float4 w = *(const float4*)(cw + (size_t)(c0 + j) * 4);
        w0[j] = w.x; w1[j] = w.y; w2[j] = w.z; w3[j] = w.w;
        bias[j] = cb[c0 + j];
    }
    #pragma unroll
    for (int s = 0; s < 8; s++) {
        bf16x8 o;
        #pragma unroll
        for (int j = 0; j < 8; j++) {
            float v = bias[j] + w0[j] * xb[s][j] + w1[j] * xb[s + 1][j]
                              + w2[j] * xb[s + 2][j] + w3[j] * xb[s + 3][j];
            o[j] = (__bf16)silu_f(v);
        }
        *(bf16x8*)(out + ((size_t)(b * SEQ + t0 + s)) * CONVD + c0) = o;
    }
}

// ---------------- chunk state (MFMA): S^T[p][n] = sum_s x[s][p]*w_s*B[s][n] ----------
__global__ __launch_bounds__(256) void chunk_state_kernel(const __bf16* __restrict__ xc,
                                                          const float* __restrict__ dtv,
                                                          const float* __restrict__ cum,
                                                          __bf16* __restrict__ Sbuf) {
    const int blk = blockIdx.x;            // ((b*NC)+c)*8 + hq
    const int hq = blk & 7;
    const int bc = blk >> 3;
    const int c = bc & (NC - 1), b = bc >> 5;
    const int tid = threadIdx.x;
    const int wave = tid >> 6, lane = tid & 63;
    const int lm = lane & 15, q = lane >> 4;
    const int h = hq * 4 + wave;

    __shared__ __align__(16) __bf16 sBt[4096];      // B^T [n][s], swizzled
    __shared__ __align__(16) __bf16 sXw[4][4096];   // (w*x)^T [p][s], swizzled

    const size_t rowbase = (size_t)b * SEQ + (size_t)c * QC;
    {
        int k = tid & 31, n0 = (tid >> 5) * 8;
        unsigned short u0[8], u1[8];
        *(uint4*)u0 = *(const uint4*)(xc + (rowbase + 2 * k) * CONVD + DIN + n0);
        *(uint4*)u1 = *(const uint4*)(xc + (rowbase + 2 * k + 1) * CONVD + DIN + n0);
        #pragma unroll
        for (int i = 0; i < 8; i++) {
            unsigned int v = (unsigned int)u0[i] | ((unsigned int)u1[i] << 16);
            ((unsigned int*)sBt)[swz(n0 + i, 2 * k) >> 1] = v;
        }
    }
    const float* cump = cum + (size_t)(b * NH + h) * SEQ + (size_t)c * QC;
    const float* dtp  = dtv + (size_t)(b * NH + h) * SEQ + (size_t)c * QC;
    {
        int k = lane & 31, ph = (lane >> 5) * 32;
        float clast = cump[63];
        float w0 = dtp[2 * k]     * __expf(clast - cump[2 * k]);
        float w1 = dtp[2 * k + 1] * __expf(clast - cump[2 * k + 1]);
        unsigned short u0[32], u1[32];
        const __bf16* r0 = xc + (rowbase + 2 * k) * CONVD + h * 64 + ph;
        const __bf16* r1 = xc + (rowbase + 2 * k + 1) * CONVD + h * 64 + ph;
        #pragma unroll
        for (int i = 0; i < 4; i++) {
            ((uint4*)u0)[i] = ((const uint4*)r0)[i];
            ((uint4*)u1)[i] = ((const uint4*)r1)[i];
        }
        unsigned int* dstw = (unsigned int*)sXw[wave];
        #pragma unroll
        for (int i = 0; i < 32; i++) {
            union { __bf16 hh; unsigned short us; } lo, hi;
            lo.hh = (__bf16)(bfbits2f(u0[i]) * w0);
            hi.hh = (__bf16)(bfbits2f(u1[i]) * w1);
            dstw[swz(ph + i, 2 * k) >> 1] = (unsigned int)lo.us | ((unsigned int)hi.us << 16);
        }
    }
    __syncthreads();

    floatx4 acc[4][4] = {};
    #pragma unroll
    for (int kb = 0; kb < 2; kb++) {
        bf16x8 aX[4], bB[4];
        #pragma unroll
        for (int pi = 0; pi < 4; pi++)
            aX[pi] = *(const bf16x8*)(&sXw[wave][swz(pi * 16 + lm, kb * 32 + q * 8)]);
        #pragma unroll
        for (int ni = 0; ni < 4; ni++)
            bB[ni] = *(const bf16x8*)(&sBt[swz(ni * 16 + lm, kb * 32 + q * 8)]);
        #pragma unroll
        for (int pi = 0; pi < 4; pi++)
            #pragma unroll
            for (int ni = 0; ni < 4; ni++)
                acc[pi][ni] = __builtin_amdgcn_mfma_f32_16x16x32_bf16(aX[pi], bB[ni], acc[pi][ni], 0, 0, 0);
    }
    __bf16* Sp = Sbuf + ((size_t)(b * NC + c) * NH + h) * (HD * DST);
    #pragma unroll
    for (int pi = 0; pi < 4; pi++)
        #pragma unroll
        for (int r = 0; r < 4; r++) {
            int p = pi * 16 + q * 4 + r;
            #pragma unroll
            for (int ni = 0; ni < 4; ni++)
                Sp[p * 64 + ni * 16 + lm] = (__bf16)acc[pi][ni][r];
        }
}

// ---------------- pass 2: inter-chunk state recurrence (in place, 512 blocks) -------
__global__ __launch_bounds__(256) void state_scan_kernel(__bf16* __restrict__ Sbuf,
                                                         const float* __restrict__ cum) {
    int blk = blockIdx.x >> 2;     // b*NH + h
    int part = blockIdx.x & 3;
    int b = blk >> 5, h = blk & 31;
    int off = part * 1024 + threadIdx.x * 4;
    float run[4];
    #pragma unroll
    for (int n = 0; n < 4; n++) run[n] = 0.f;
    for (int c = 0; c < NC; c++) {
        __bf16* Sp = Sbuf + ((size_t)(b * NC + c) * NH + h) * (HD * DST) + off;
        bf16x4 sv = *(const bf16x4*)Sp;
        float tmp[4];
        #pragma unroll
        for (int n = 0; n < 4; n++) tmp[n] = (float)sv[n];
        bf16x4 ov;
        #pragma unroll
        for (int n = 0; n < 4; n++) ov[n] = (__bf16)run[n];
        *(bf16x4*)Sp = ov;                                  // slot c <- state before chunk c
        float P = __expf(cum[(size_t)blk * SEQ + c * QC + QC - 1]);
        #pragma unroll
        for (int n = 0; n < 4; n++) run[n] = fmaf(run[n], P, tmp[n]);
    }
}

// ---------------- chunk output (MFMA) + silu(z) gate + rowsum ----------------
// Y = exp(cum_t)*C@S_prev + (M o C@B^T + D*I)@X ; g = Y*silu(z) -> tiled yf
__global__ __launch_bounds__(128) void chunk_out_kernel(const __bf16* __restrict__ xc,
                                                        const float* __restrict__ dtv,
                                                        const float* __restrict__ cum,
                                                        const __bf16* __restrict__ Sbuf,
                                                        const float* __restrict__ Dv,
                                                        const __bf16* __restrict__ zx,
                                                        float* __restrict__ rowsum,
                                                        __bf16* __restrict__ y) {
    const int blk = blockIdx.x;           // ((b*NC)+c)*16 + hp
    const int hp = blk & 15;
    const int bc = blk >> 4;
    const int c = bc & (NC - 1), b = bc >> 5;
    const int tid = threadIdx.x;
    const int wave = tid >> 6, lane = tid & 63;
    const int lm = lane & 15, q = lane >> 4;
    const int h = hp * 2 + wave;

    __shared__ __align__(16) __bf16 smem[16384];     // 32 KB
    __bf16* sB  = smem;                              // B [s][n] swizzled (shared)
    __bf16* sC  = smem + 4096;                       // C [t][n] swizzled (shared)
    __bf16* sXt = smem + 8192 + (wave << 12);        // x^T [p][s] swizzled (per wave)
    __bf16* sP  = smem + (wave << 12);               // P aliases sB (w0) / sC (w1)

    const size_t rowbase = (size_t)b * SEQ + (size_t)c * QC;
    {
        int r = tid >> 1, c0 = (tid & 1) * 32;
        const __bf16* gB = xc + (rowbase + r) * CONVD + DIN + c0;
        const __bf16* gC = xc + (rowbase + r) * CONVD + DIN + DST + c0;
        #pragma unroll
        for (int i = 0; i < 4; i++) {
            *(uint4*)(&sB[swz(r, c0 + i * 8)]) = *(const uint4*)(gB + i * 8);
            *(uint4*)(&sC[swz(r, c0 + i * 8)]) = *(const uint4*)(gC + i * 8);
        }
    }
    {
        int k = lane & 31, ph = (lane >> 5) * 32;
        unsigned short u0[32], u1[32];
        const __bf16* r0 = xc + (rowbase + 2 * k) * CONVD + h * 64 + ph;
        const __bf16* r1 = xc + (rowbase + 2 * k + 1) * CONVD + h * 64 + ph;
        #pragma unroll
        for (int i = 0; i < 4; i++) {
            ((uint4*)u0)[i] = ((const uint4*)r0)[i];
            ((uint4*)u1)[i] = ((const uint4*)r1)[i];
        }
        unsigned int* dstw = (unsigned int*)sXt;
        #pragma unroll
        for (int i = 0; i < 32; i++)
            dstw[swz(ph + i, 2 * k) >> 1] = (unsigned int)u0[i] | ((unsigned int)u1[i] << 16);
    }
    __syncthreads();

    const float* cump = cum + (size_t)(b * NH + h) * SEQ + (size_t)c * QC;
    const float* dtp  = dtv + (size_t)(b * NH + h) * SEQ + (size_t)c * QC;
    float cumv = cump[lane], dtvv = dtp[lane];
    float ct[4][4];
    #pragma unroll
    for (int ti = 0; ti < 4; ti++)
        #pragma unroll
        for (int r = 0; r < 4; r++)
            ct[ti][r] = __shfl(cumv, ti * 16 + q * 4 + r);
    float cums_l[4], dtv_l[4];
    #pragma unroll
    for (int si = 0; si < 4; si++) {
        cums_l[si] = __shfl(cumv, si * 16 + lm);
        dtv_l[si]  = __shfl(dtvv, si * 16 + lm);
    }

    bf16x8 afC[4][2];
    #pragma unroll
    for (int ti = 0; ti < 4; ti++)
        #pragma unroll
        for (int kb = 0; kb < 2; kb++)
            afC[ti][kb] = *(const bf16x8*)(&sC[swz(ti * 16 + lm, kb * 32 + q * 8)]);

    // G = C @ B^T (triangular tiles si<=ti)
    floatx4 accG[4][4] = {};
    #pragma unroll
    for (int kb = 0; kb < 2; kb++) {
        bf16x8 bfB[4];
        #pragma unroll
        for (int si = 0; si < 4; si++)
            bfB[si] = *(const bf16x8*)(&sB[swz(si * 16 + lm, kb * 32 + q * 8)]);
        #pragma unroll
        for (int ti = 0; ti < 4; ti++)
            #pragma unroll
            for (int si = 0; si < 4; si++)
                if (si <= ti)
                    accG[ti][si] = __builtin_amdgcn_mfma_f32_16x16x32_bf16(afC[ti][kb], bfB[si], accG[ti][si], 0, 0, 0);
    }
    __syncthreads();   // all waves done reading sB/sC -> safe to overwrite with P

    // mask + decay -> P (bf16, swizzled [t][s]); D folded onto the diagonal
    float Dh = Dv[h];
    #pragma unroll
    for (int ti = 0; ti < 4; ti++)
        #pragma unroll
        for (int si = 0; si < 4; si++) {
            if (si > ti) continue;
            #pragma unroll
            for (int r = 0; r < 4; r++) {
                int t = ti * 16 + q * 4 + r;
                float arg = fminf(ct[ti][r] - cums_l[si], 0.f);
                float val = dtv_l[si] * __expf(arg) * accG[ti][si][r];
                if (ti == si) {
                    if (lm > q * 4 + r) val = 0.f;
                    else if (lm == q * 4 + r) val += Dh;
                }
                sP[swz(t, si * 16 + lm)] = (__bf16)val;
            }
        }
    #pragma unroll
    for (int r = 0; r < 4; r++) {   // zero tiles (0,1) and (2,3)
        sP[swz(q * 4 + r, 16 + lm)] = (__bf16)0.f;
        sP[swz(32 + q * 4 + r, 48 + lm)] = (__bf16)0.f;
    }
    __syncthreads();

    // inter-chunk: Y = C @ S_prev, then row-scale by exp(cum_t)
    floatx4 accY[4][4] = {};
    const __bf16* Sp = Sbuf + ((size_t)(b * NC + c) * NH + h) * (HD * DST);
    #pragma unroll
    for (int kb = 0; kb < 2; kb++) {
        bf16x8 bS[4];
        #pragma unroll
        for (int pi = 0; pi < 4; pi++)
            bS[pi] = *(const bf16x8*)(Sp + (pi * 16 + lm) * 64 + kb * 32 + q * 8);
        #pragma unroll
        for (int ti = 0; ti < 4; ti++)
            #pragma unroll
            for (int pi = 0; pi < 4; pi++)
                accY[ti][pi] = __builtin_amdgcn_mfma_f32_16x16x32_bf16(afC[ti][kb], bS[pi], accY[ti][pi], 0, 0, 0);
    }
    #pragma unroll
    for (int ti = 0; ti < 4; ti++)
        #pragma unroll
        for (int r = 0; r < 4; r++) {
            float e = __expf(ct[ti][r]);
            #pragma unroll
            for (int pi = 0; pi < 4; pi++)
                accY[ti][pi][r] *= e;
        }

    // intra: Y += P @ X (skip fully-masked k-blocks)
    #pragma unroll
    for (int kb = 0; kb < 2; kb++) {
        bf16x8 bX[4];
        #pragma unroll
        for (int pi = 0; pi < 4; pi++)
            bX[pi] = *(const bf16x8*)(&sXt[swz(pi * 16 + lm, kb * 32 + q * 8)]);
        #pragma unroll
        for (int ti = 0; ti < 4; ti++) {
            if (ti < 2 * kb) continue;
            bf16x8 aP = *(const bf16x8*)(&sP[swz(ti * 16 + lm, kb * 32 + q * 8)]);
            #pragma unroll
            for (int pi = 0; pi < 4; pi++)
                accY[ti][pi] = __builtin_amdgcn_mfma_f32_16x16x32_bf16(aP, bX[pi], accY[ti][pi], 0, 0, 0);
        }
    }

    // gate with silu(z), store into TILED yf, accumulate rowsum
    const int R4v = (int)(rowbase >> 4);
    #pragma unroll
    for (int ti = 0; ti < 4; ti++) {
        __bf16* slab = y + (size_t)(R4v + ti) * 32768;
        #pragma unroll
        for (int r = 0; r < 4; r++) {
            int t = ti * 16 + q * 4 + r;
            const __bf16* zrow = zx + (rowbase + t) * NPROJ + h * 64;
            float rs = 0.f;
            #pragma unroll
            for (int pi = 0; pi < 4; pi++) {
                float zv = (float)zrow[pi * 16 + lm];
                float g = accY[ti][pi][r] * silu_f(zv);
                rs += g * g;
                int kbC = h * 2 + (pi >> 1);
                int qC  = ((pi & 1) << 1) + (lm >> 3);
                slab[kbC * 512 + qC * 128 + (lm & 7) + (q * 4 + r) * 8] = (__bf16)g;
            }
            rs += __shfl_xor(rs, 1);
            rs += __shfl_xor(rs, 2);
            rs += __shfl_xor(rs, 4);
            rs += __shfl_xor(rs, 8);
            if (lm == 0) atomicAdd(&rowsum[rowbase + t], rs);
        }
    }
}

// ---------------- launch ----------------
extern "C" void kernel_launch(void* const* d_in, const int* in_sizes, int n_in,
                              void* d_out, int out_size, void* d_ws, size_t ws_size,
                              hipStream_t stream) {
    const float* x       = (const float*)d_in[0];
    const float* W_in    = (const float*)d_in[1];
    const float* conv_w  = (const float*)d_in[2];
    const float* conv_b  = (const float*)d_in[3];
    const float* dt_bias = (const float*)d_in[4];
    const float* A_log   = (const float*)d_in[5];
    const float* Dv      = (const float*)d_in[6];
    const float* norm_w  = (const float*)d_in[7];
    const float* W_out   = (const float*)d_in[8];
    float* out = (float*)d_out;

    char* ws = (char*)d_ws;
    size_t off = 0;
    auto take = [&](size_t bytes) { void* p = ws + off; off = (off + bytes + 255) & ~(size_t)255; return p; };
    __bf16* xbf    = (__bf16*)take((size_t)MROWS * DM * 2);          // 16.8 MB (tiled)
    __bf16* WinT   = (__bf16*)take((size_t)NPROJ * DM * 2);          //  8.7 MB (tiled)
    __bf16* WoutT  = (__bf16*)take((size_t)DM * DIN * 2);            //  4.2 MB (tiled, *norm_w)
    __bf16* zx     = (__bf16*)take((size_t)MROWS * NPROJ * 2);       // 69.2 MB (row-major)
    __bf16* xc     = (__bf16*)take((size_t)MROWS * CONVD * 2);       // 35.7 MB (row-major)
    __bf16* yf     = (__bf16*)take((size_t)MROWS * DIN * 2);         // 33.6 MB (tiled, gated)
    float*  dtraw  = (float*) take((size_t)MROWS * NH * 4);          //  1.0 MB
    float*  dtv    = (float*) take((size_t)B_SZ * NH * SEQ * 4);     //  1.0 MB
    float*  cum    = (float*) take((size_t)B_SZ * NH * SEQ * 4);     //  1.0 MB
    __bf16* Sbuf   = (__bf16*)take((size_t)B_SZ * NC * NH * HD * DST * 2); // 33.6 MB
    float*  dtWc   = (float*) take((size_t)DM * NH * 4);             //  0.13 MB
    float*  rowsum = (float*) take((size_t)MROWS * 4);               //  32 KB
    (void)ws_size;                                                    // total ~205 MB

    // 1. weight prep: dtWc + tiled W_in^T + tiled (W_out*norm_w)^T
    prep_weights_kernel<<<dim3(1696), 256, 0, stream>>>(W_in, W_out, norm_w, dtWc, WinT, WoutT);
    // 2. fused x->tiled bf16 + fp32 dt projection (2048 blocks, 4 rows each)
    cvt_dt_kernel<<<dim3(MROWS / 4), 256, 0, stream>>>(x, dtWc, xbf, dtraw);
    // 3. GEMM1 (zx = x @ W_in[:,:4224]) + dt softplus/cumsum + rowsum zeroing
    gemm1_kernel<<<dim3(2248), 256, 0, stream>>>(xbf, WinT, zx,
                                                 dtraw, dt_bias, A_log, dtv, cum, rowsum);
    // 4. depthwise conv + silu -> xc
    conv_silu_kernel<<<dim3(17, 64), 256, 0, stream>>>(zx, conv_w, conv_b, xc);
    // 5. chunk-local states via MFMA (1024 blocks x 4 waves)
    chunk_state_kernel<<<dim3(B_SZ * NC * (NH / 4)), 256, 0, stream>>>(xc, dtv, cum, Sbuf);
    // 6. inter-chunk state recurrence (512 blocks)
    state_scan_kernel<<<dim3(B_SZ * NH * 4), 256, 0, stream>>>(Sbuf, cum);
    // 7. chunk outputs via MFMA + gate + rowsum -> tiled yf (2048 blocks x 2 waves)
    chunk_out_kernel<<<dim3(B_SZ * NC * (NH / 2)), 128, 0, stream>>>(
        xc, dtv, cum, Sbuf, Dv, zx, rowsum, yf);
    // 8. GEMM2: out = rmsnorm-scale(yf) @ (W_out*norm_w) (fp32 out)
    gemm2_kernel<<<dim3(MROWS / 128, DM / 128), 256, 0, stream>>>(yf, WoutT, out, rowsum);
}